// Round 1
// baseline (241.254 us; speedup 1.0000x reference)
//
#include <hip/hip_runtime.h>
#include <hip/hip_bf16.h>

// Problem: NT-Xent loss. N=4096 pairs, D=1024, 2N=8192 rows total.
// loss = 1/T + mean_i log( sum_{j != i} exp(sim_ij - 1/T) ) - mean_i pos_i
// with sim = Z Z^T / T, Z row-normalized concat of the two views.
// Fixed max = 1/T is valid since sim_ij <= 1/T (cosine bound) -> no online max.

#define NPAIR 4096
#define NROWS 8192
#define DIM   1024
#define INV_T 14.285714285714286f   // 1/0.07

typedef __attribute__((ext_vector_type(8))) __bf16 bf16x8;
typedef __attribute__((ext_vector_type(4))) float  f32x4;

#define GLOAD_LDS16(g, l)                                              \
  __builtin_amdgcn_global_load_lds(                                    \
      (const __attribute__((address_space(1))) void*)(g),              \
      (__attribute__((address_space(3))) void*)(l), 16, 0, 0)

static __device__ __forceinline__ unsigned short f2bf(float x) {
  unsigned u = __builtin_bit_cast(unsigned, x);
  unsigned r = u + 0x7FFFu + ((u >> 16) & 1u);   // RNE to bf16
  return (unsigned short)(r >> 16);
}

// ---------------------------------------------------------------------------
// Kernel A: per pair-row i, compute norms of both views + their dot,
// write bf16-normalized rows Z[i] and Z[i+NPAIR], and pos[i] = cos/T (fp32).
// ---------------------------------------------------------------------------
__global__ __launch_bounds__(256) void normalize_kernel(
    const float* __restrict__ l1, const float* __restrict__ l2,
    __hip_bfloat16* __restrict__ Z, float* __restrict__ pos) {
  const int i = blockIdx.x;
  const int t = threadIdx.x;           // 0..255, one float4 per thread
  const float4 a = ((const float4*)(l1 + (size_t)i * DIM))[t];
  const float4 b = ((const float4*)(l2 + (size_t)i * DIM))[t];
  float s1 = a.x*a.x + a.y*a.y + a.z*a.z + a.w*a.w;
  float s2 = b.x*b.x + b.y*b.y + b.z*b.z + b.w*b.w;
  float d  = a.x*b.x + a.y*b.y + a.z*b.z + a.w*b.w;

  #pragma unroll
  for (int off = 32; off; off >>= 1) {
    s1 += __shfl_down(s1, off);
    s2 += __shfl_down(s2, off);
    d  += __shfl_down(d,  off);
  }
  __shared__ float red[3][4];
  __shared__ float fin[3];
  const int wave = t >> 6, lane = t & 63;
  if (lane == 0) { red[0][wave] = s1; red[1][wave] = s2; red[2][wave] = d; }
  __syncthreads();
  if (t == 0) {
    float S1 = red[0][0] + red[0][1] + red[0][2] + red[0][3];
    float S2 = red[1][0] + red[1][1] + red[1][2] + red[1][3];
    float DD = red[2][0] + red[2][1] + red[2][2] + red[2][3];
    float r1 = rsqrtf(S1), r2 = rsqrtf(S2);
    fin[0] = r1; fin[1] = r2;
    pos[i] = DD * r1 * r2 * INV_T;
  }
  __syncthreads();
  const float r1 = fin[0], r2 = fin[1];
  ushort4 za, zb;
  za.x = f2bf(a.x * r1); za.y = f2bf(a.y * r1);
  za.z = f2bf(a.z * r1); za.w = f2bf(a.w * r1);
  zb.x = f2bf(b.x * r2); zb.y = f2bf(b.y * r2);
  zb.z = f2bf(b.z * r2); zb.w = f2bf(b.w * r2);
  ((ushort4*)(Z + (size_t)i * DIM))[t] = za;
  ((ushort4*)(Z + (size_t)(i + NPAIR) * DIM))[t] = zb;
}

// ---------------------------------------------------------------------------
// Kernel B: 128x128 tile of sim = Z Z^T (bf16 MFMA, fp32 acc), fused
// exp((acc-1)/T) with diagonal mask, per-row partial sums -> atomicAdd.
// Both operands are row-major K-contiguous (gemm_bt pattern).
// ---------------------------------------------------------------------------
__global__ __launch_bounds__(256) void ntxent_gemm_kernel(
    const __hip_bfloat16* __restrict__ Z, float* __restrict__ rowsum) {
  __shared__ __hip_bfloat16 As[128 * 64];
  __shared__ __hip_bfloat16 Bs[128 * 64];
  const int t    = threadIdx.x;
  const int wave = t >> 6;
  const int lane = t & 63;
  const int brow = blockIdx.y * 128;
  const int bcol = blockIdx.x * 128;
  const int wr = wave >> 1, wc = wave & 1;   // 2x2 waves, 64x64 each
  const int lrow = lane & 15;
  const int kgrp = lane >> 4;

  f32x4 acc[4][4];
  #pragma unroll
  for (int i = 0; i < 4; ++i)
    #pragma unroll
    for (int j = 0; j < 4; ++j) acc[i][j] = (f32x4){0.f, 0.f, 0.f, 0.f};

  for (int k0 = 0; k0 < DIM; k0 += 64) {
    if (k0) __syncthreads();
    #pragma unroll
    for (int it = 0; it < 4; ++it) {
      const int cb = it * 256 + wave * 64;   // wave-uniform chunk base
      const int c  = cb + lane;              // 16B chunk id, row = c>>3
      const __hip_bfloat16* ga = Z + (size_t)(brow + (c >> 3)) * DIM + k0 + (c & 7) * 8;
      GLOAD_LDS16(ga, &As[cb * 8]);
      const __hip_bfloat16* gb = Z + (size_t)(bcol + (c >> 3)) * DIM + k0 + (c & 7) * 8;
      GLOAD_LDS16(gb, &Bs[cb * 8]);
    }
    __syncthreads();
    #pragma unroll
    for (int kk = 0; kk < 2; ++kk) {
      bf16x8 af[4], bfr[4];
      #pragma unroll
      for (int mi = 0; mi < 4; ++mi)
        af[mi] = *(const bf16x8*)&As[(wr * 64 + mi * 16 + lrow) * 64 + kk * 32 + kgrp * 8];
      #pragma unroll
      for (int ni = 0; ni < 4; ++ni)
        bfr[ni] = *(const bf16x8*)&Bs[(wc * 64 + ni * 16 + lrow) * 64 + kk * 32 + kgrp * 8];
      #pragma unroll
      for (int mi = 0; mi < 4; ++mi)
        #pragma unroll
        for (int ni = 0; ni < 4; ++ni)
          acc[mi][ni] = __builtin_amdgcn_mfma_f32_16x16x32_bf16(af[mi], bfr[ni], acc[mi][ni], 0, 0, 0);
    }
  }

  // Epilogue: C/D layout col=lane&15, row=(lane>>4)*4+j  (m89-verified).
  #pragma unroll
  for (int mi = 0; mi < 4; ++mi) {
    float rs[4] = {0.f, 0.f, 0.f, 0.f};
    #pragma unroll
    for (int ni = 0; ni < 4; ++ni) {
      const int gcol = bcol + wc * 64 + ni * 16 + lrow;
      #pragma unroll
      for (int j = 0; j < 4; ++j) {
        const int grow = brow + wr * 64 + mi * 16 + kgrp * 4 + j;
        const float v = acc[mi][ni][j];
        const float e = (grow == gcol) ? 0.f : __expf((v - 1.0f) * INV_T);
        rs[j] += e;
      }
    }
    #pragma unroll
    for (int j = 0; j < 4; ++j) {
      float s = rs[j];
      s += __shfl_xor(s, 1);
      s += __shfl_xor(s, 2);
      s += __shfl_xor(s, 4);
      s += __shfl_xor(s, 8);
      if (lrow == 0) {
        const int grow = brow + wr * 64 + mi * 16 + kgrp * 4 + j;
        atomicAdd(&rowsum[grow], s);
      }
    }
  }
}

// ---------------------------------------------------------------------------
// Kernel C: loss = 1/T + mean(log rowsum) - mean(pos)
// ---------------------------------------------------------------------------
__global__ __launch_bounds__(256) void finalize_kernel(
    const float* __restrict__ rowsum, const float* __restrict__ pos,
    float* __restrict__ out) {
  const int t = threadIdx.x;
  float ls = 0.f, ps = 0.f;
  for (int i = t; i < NROWS; i += 256) ls += logf(rowsum[i]);
  for (int i = t; i < NPAIR; i += 256) ps += pos[i];
  #pragma unroll
  for (int off = 32; off; off >>= 1) {
    ls += __shfl_down(ls, off);
    ps += __shfl_down(ps, off);
  }
  __shared__ float sls[4], sps[4];
  const int wave = t >> 6, lane = t & 63;
  if (lane == 0) { sls[wave] = ls; sps[wave] = ps; }
  __syncthreads();
  if (t == 0) {
    const float LS = sls[0] + sls[1] + sls[2] + sls[3];
    const float PS = sps[0] + sps[1] + sps[2] + sps[3];
    out[0] = INV_T + LS / (float)NROWS - PS / (float)NPAIR;
  }
}

extern "C" void kernel_launch(void* const* d_in, const int* in_sizes, int n_in,
                              void* d_out, int out_size, void* d_ws, size_t ws_size,
                              hipStream_t stream) {
  const float* l1 = (const float*)d_in[0];
  const float* l2 = (const float*)d_in[1];
  float* out = (float*)d_out;

  char* ws = (char*)d_ws;
  __hip_bfloat16* Z = (__hip_bfloat16*)ws;                       // 16 MB
  float* rowsum = (float*)(ws + (size_t)NROWS * DIM * 2);        // 32 KB
  float* pos    = rowsum + NROWS;                                // 16 KB

  hipMemsetAsync(rowsum, 0, NROWS * sizeof(float), stream);
  normalize_kernel<<<NPAIR, 256, 0, stream>>>(l1, l2, Z, pos);
  dim3 grid(NROWS / 128, NROWS / 128);
  ntxent_gemm_kernel<<<grid, 256, 0, stream>>>(Z, rowsum);
  finalize_kernel<<<1, 256, 0, stream>>>(rowsum, pos, out);
}

// Round 2
// 136.642 us; speedup vs baseline: 1.7656x; 1.7656x over previous
//
#include <hip/hip_runtime.h>
#include <hip/hip_bf16.h>

// NT-Xent loss. N=4096 pairs, D=1024, 2N=8192 rows.
// loss = 1/T + mean_i log( sum_{j != i} exp(sim_ij - 1/T) ) - mean_i pos_i
// sim = Z Z^T (cosine), fixed max 1/T (cosine bound) -> no online max.
// R2: exploit symmetry e_ij = e_ji -> compute only upper-triangular tiles
// (2080/4096 = 50.8% of MFMA work); off-diag tiles feed BOTH row-sums and
// column-sums of the exp matrix.

#define NPAIR 4096
#define NROWS 8192
#define DIM   1024
#define NTILE 64                    // 8192 / 128
#define NTRI  (NTILE * (NTILE + 1) / 2)   // 2080
#define INV_T 14.285714285714286f   // 1/0.07

typedef __attribute__((ext_vector_type(8))) __bf16 bf16x8;
typedef __attribute__((ext_vector_type(4))) float  f32x4;

#define GLOAD_LDS16(g, l)                                              \
  __builtin_amdgcn_global_load_lds(                                    \
      (const __attribute__((address_space(1))) void*)(g),              \
      (__attribute__((address_space(3))) void*)(l), 16, 0, 0)

static __device__ __forceinline__ unsigned short f2bf(float x) {
  unsigned u = __builtin_bit_cast(unsigned, x);
  unsigned r = u + 0x7FFFu + ((u >> 16) & 1u);   // RNE to bf16
  return (unsigned short)(r >> 16);
}

// ---------------------------------------------------------------------------
// Kernel A: per pair-row i: norms of both views + cross dot; write bf16
// normalized Z[i], Z[i+NPAIR]; pos[i] = cos/T (fp32).
// ---------------------------------------------------------------------------
__global__ __launch_bounds__(256) void normalize_kernel(
    const float* __restrict__ l1, const float* __restrict__ l2,
    __hip_bfloat16* __restrict__ Z, float* __restrict__ pos) {
  const int i = blockIdx.x;
  const int t = threadIdx.x;           // one float4 per thread
  const float4 a = ((const float4*)(l1 + (size_t)i * DIM))[t];
  const float4 b = ((const float4*)(l2 + (size_t)i * DIM))[t];
  float s1 = a.x*a.x + a.y*a.y + a.z*a.z + a.w*a.w;
  float s2 = b.x*b.x + b.y*b.y + b.z*b.z + b.w*b.w;
  float d  = a.x*b.x + a.y*b.y + a.z*b.z + a.w*b.w;

  #pragma unroll
  for (int off = 32; off; off >>= 1) {
    s1 += __shfl_down(s1, off);
    s2 += __shfl_down(s2, off);
    d  += __shfl_down(d,  off);
  }
  __shared__ float red[3][4];
  __shared__ float fin[3];
  const int wave = t >> 6, lane = t & 63;
  if (lane == 0) { red[0][wave] = s1; red[1][wave] = s2; red[2][wave] = d; }
  __syncthreads();
  if (t == 0) {
    float S1 = red[0][0] + red[0][1] + red[0][2] + red[0][3];
    float S2 = red[1][0] + red[1][1] + red[1][2] + red[1][3];
    float DD = red[2][0] + red[2][1] + red[2][2] + red[2][3];
    float r1 = rsqrtf(S1), r2 = rsqrtf(S2);
    fin[0] = r1; fin[1] = r2;
    pos[i] = DD * r1 * r2 * INV_T;
  }
  __syncthreads();
  const float r1 = fin[0], r2 = fin[1];
  ushort4 za, zb;
  za.x = f2bf(a.x * r1); za.y = f2bf(a.y * r1);
  za.z = f2bf(a.z * r1); za.w = f2bf(a.w * r1);
  zb.x = f2bf(b.x * r2); zb.y = f2bf(b.y * r2);
  zb.z = f2bf(b.z * r2); zb.w = f2bf(b.w * r2);
  ((ushort4*)(Z + (size_t)i * DIM))[t] = za;
  ((ushort4*)(Z + (size_t)(i + NPAIR) * DIM))[t] = zb;
}

// ---------------------------------------------------------------------------
// Kernel B: upper-triangular 128x128 tiles of sim = Z Z^T (bf16 MFMA).
// acc -> exp((acc-1)/T) in place (diag-masked), then row-sums (always) and
// col-sums (off-diag tiles only) atomically accumulated into rowsum[8192].
// ---------------------------------------------------------------------------
__global__ __launch_bounds__(256) void ntxent_gemm_kernel(
    const __hip_bfloat16* __restrict__ Z, float* __restrict__ rowsum) {
  __shared__ __hip_bfloat16 As[128 * 64];
  __shared__ __hip_bfloat16 Bs[128 * 64];
  const int t    = threadIdx.x;
  const int wave = t >> 6;
  const int lane = t & 63;

  // decode linear idx -> (bi, bj) with bi <= bj (column-major upper triangle)
  const int idx = blockIdx.x;
  int bj = (int)((sqrtf(8.0f * (float)idx + 1.0f) - 1.0f) * 0.5f);
  while ((bj + 1) * (bj + 2) / 2 <= idx) ++bj;
  while (bj * (bj + 1) / 2 > idx) --bj;
  const int bi = idx - bj * (bj + 1) / 2;

  const int brow = bi * 128;
  const int bcol = bj * 128;
  const bool diag = (bi == bj);

  const int wr = wave >> 1, wc = wave & 1;   // 2x2 waves, 64x64 each
  const int lrow = lane & 15;
  const int kgrp = lane >> 4;

  f32x4 acc[4][4];
  #pragma unroll
  for (int i = 0; i < 4; ++i)
    #pragma unroll
    for (int j = 0; j < 4; ++j) acc[i][j] = (f32x4){0.f, 0.f, 0.f, 0.f};

  for (int k0 = 0; k0 < DIM; k0 += 64) {
    if (k0) __syncthreads();
    #pragma unroll
    for (int it = 0; it < 4; ++it) {
      const int cb = it * 256 + wave * 64;   // wave-uniform chunk base
      const int c  = cb + lane;              // 16B chunk id, row = c>>3
      const __hip_bfloat16* ga = Z + (size_t)(brow + (c >> 3)) * DIM + k0 + (c & 7) * 8;
      GLOAD_LDS16(ga, &As[cb * 8]);
      const __hip_bfloat16* gb = Z + (size_t)(bcol + (c >> 3)) * DIM + k0 + (c & 7) * 8;
      GLOAD_LDS16(gb, &Bs[cb * 8]);
    }
    __syncthreads();
    #pragma unroll
    for (int kk = 0; kk < 2; ++kk) {
      bf16x8 af[4], bfr[4];
      #pragma unroll
      for (int mi = 0; mi < 4; ++mi)
        af[mi] = *(const bf16x8*)&As[(wr * 64 + mi * 16 + lrow) * 64 + kk * 32 + kgrp * 8];
      #pragma unroll
      for (int ni = 0; ni < 4; ++ni)
        bfr[ni] = *(const bf16x8*)&Bs[(wc * 64 + ni * 16 + lrow) * 64 + kk * 32 + kgrp * 8];
      #pragma unroll
      for (int mi = 0; mi < 4; ++mi)
        #pragma unroll
        for (int ni = 0; ni < 4; ++ni)
          acc[mi][ni] = __builtin_amdgcn_mfma_f32_16x16x32_bf16(af[mi], bfr[ni], acc[mi][ni], 0, 0, 0);
    }
  }

  // C/D layout (m89-verified): col = lane&15, row = (lane>>4)*4 + j.
  // Transform acc -> exp values in place, masking the true diagonal.
  #pragma unroll
  for (int mi = 0; mi < 4; ++mi)
    #pragma unroll
    for (int ni = 0; ni < 4; ++ni) {
      const int gcol = bcol + wc * 64 + ni * 16 + lrow;
      #pragma unroll
      for (int j = 0; j < 4; ++j) {
        const int grow = brow + wr * 64 + mi * 16 + kgrp * 4 + j;
        const float v = acc[mi][ni][j];
        acc[mi][ni][j] = (grow == gcol) ? 0.f : __expf((v - 1.0f) * INV_T);
      }
    }

  // Row sums: reduce over ni (lane-local) then across lrow (xor 1,2,4,8).
  #pragma unroll
  for (int mi = 0; mi < 4; ++mi) {
    float rs[4] = {0.f, 0.f, 0.f, 0.f};
    #pragma unroll
    for (int ni = 0; ni < 4; ++ni)
      #pragma unroll
      for (int j = 0; j < 4; ++j) rs[j] += acc[mi][ni][j];
    #pragma unroll
    for (int j = 0; j < 4; ++j) {
      float s = rs[j];
      s += __shfl_xor(s, 1);
      s += __shfl_xor(s, 2);
      s += __shfl_xor(s, 4);
      s += __shfl_xor(s, 8);
      if (lrow == 0) {
        const int grow = brow + wr * 64 + mi * 16 + kgrp * 4 + j;
        atomicAdd(&rowsum[grow], s);
      }
    }
  }

  // Col sums (off-diagonal tiles only): reduce over mi,j (lane-local) then
  // across kgrp (xor 16, 32); lanes 0..15 of each wave commit 16 columns.
  if (!diag) {
    #pragma unroll
    for (int ni = 0; ni < 4; ++ni) {
      float cs = 0.f;
      #pragma unroll
      for (int mi = 0; mi < 4; ++mi)
        cs += acc[mi][ni][0] + acc[mi][ni][1] + acc[mi][ni][2] + acc[mi][ni][3];
      cs += __shfl_xor(cs, 16);
      cs += __shfl_xor(cs, 32);
      if (kgrp == 0) {
        const int gcol = bcol + wc * 64 + ni * 16 + lrow;
        atomicAdd(&rowsum[gcol], cs);
      }
    }
  }
}

// ---------------------------------------------------------------------------
// Kernel C: loss = 1/T + mean(log rowsum) - mean(pos)
// ---------------------------------------------------------------------------
__global__ __launch_bounds__(256) void finalize_kernel(
    const float* __restrict__ rowsum, const float* __restrict__ pos,
    float* __restrict__ out) {
  const int t = threadIdx.x;
  float ls = 0.f, ps = 0.f;
  for (int i = t; i < NROWS; i += 256) ls += logf(rowsum[i]);
  for (int i = t; i < NPAIR; i += 256) ps += pos[i];
  #pragma unroll
  for (int off = 32; off; off >>= 1) {
    ls += __shfl_down(ls, off);
    ps += __shfl_down(ps, off);
  }
  __shared__ float sls[4], sps[4];
  const int wave = t >> 6, lane = t & 63;
  if (lane == 0) { sls[wave] = ls; sps[wave] = ps; }
  __syncthreads();
  if (t == 0) {
    const float LS = sls[0] + sls[1] + sls[2] + sls[3];
    const float PS = sps[0] + sps[1] + sps[2] + sps[3];
    out[0] = INV_T + LS / (float)NROWS - PS / (float)NPAIR;
  }
}

extern "C" void kernel_launch(void* const* d_in, const int* in_sizes, int n_in,
                              void* d_out, int out_size, void* d_ws, size_t ws_size,
                              hipStream_t stream) {
  const float* l1 = (const float*)d_in[0];
  const float* l2 = (const float*)d_in[1];
  float* out = (float*)d_out;

  char* ws = (char*)d_ws;
  __hip_bfloat16* Z = (__hip_bfloat16*)ws;                       // 16 MB
  float* rowsum = (float*)(ws + (size_t)NROWS * DIM * 2);        // 32 KB
  float* pos    = rowsum + NROWS;                                // 16 KB

  hipMemsetAsync(rowsum, 0, NROWS * sizeof(float), stream);
  normalize_kernel<<<NPAIR, 256, 0, stream>>>(l1, l2, Z, pos);
  ntxent_gemm_kernel<<<NTRI, 256, 0, stream>>>(Z, rowsum);
  finalize_kernel<<<1, 256, 0, stream>>>(rowsum, pos, out);
}

// Round 3
// 132.132 us; speedup vs baseline: 1.8259x; 1.0341x over previous
//
#include <hip/hip_runtime.h>
#include <hip/hip_bf16.h>

// NT-Xent loss. N=4096 pairs, D=1024, 2N=8192 rows.
// loss = 1/T + mean_i log( sum_{j != i} exp(sim_ij - 1/T) ) - mean_i pos_i
// sim = Z Z^T (cosine), fixed max 1/T (cosine bound) -> no online max.
// R2: triangular tiles (symmetry: e_ij = e_ji feeds row+col sums).
// R3: 256x256 8-phase deep-pipelined GEMM (T1+T2+T3+T4+T5 stack):
//   - 8 waves (2Mx4N), BK=64, acc[8][4], 16 MFMA per phase
//   - LDS = 8 half-slots (2buf x {A,B} x 2halves x 16KB) = 128 KB
//   - stage 1 half-tile/phase via global_load_lds w16, counted vmcnt(4)
//     at phase-3/7 boundaries only (never 0 in steady state)
//   - XOR chunk swizzle on ds_read + inverse-swizzled global source
//   - raw s_barrier + lgkmcnt(0) + setprio around MFMA cluster

#define NPAIR 4096
#define NROWS 8192
#define DIM   1024
#define NTILE 32                          // 8192 / 256
#define NTRI  (NTILE * (NTILE + 1) / 2)   // 528
#define NITER 8                           // 16 K-tiles, 2 per iteration
#define INV_T 14.285714285714286f         // 1/0.07

typedef __attribute__((ext_vector_type(8))) __bf16 bf16x8;
typedef __attribute__((ext_vector_type(4))) float  f32x4;

#define GLOAD_LDS16(g, l)                                              \
  __builtin_amdgcn_global_load_lds(                                    \
      (const __attribute__((address_space(1))) void*)(g),              \
      (__attribute__((address_space(3))) void*)(l), 16, 0, 0)

#define BAR()   __builtin_amdgcn_s_barrier()
#define WAITL() { asm volatile("s_waitcnt lgkmcnt(0)" ::: "memory");   \
                  __builtin_amdgcn_sched_barrier(0); }
#define WAIT_VM(N) asm volatile("s_waitcnt vmcnt(" #N ")" ::: "memory")

static __device__ __forceinline__ unsigned short f2bf(float x) {
  unsigned u = __builtin_bit_cast(unsigned, x);
  unsigned r = u + 0x7FFFu + ((u >> 16) & 1u);   // RNE to bf16
  return (unsigned short)(r >> 16);
}

// ---------------------------------------------------------------------------
// Kernel A: per pair-row i: norms of both views + cross dot; write bf16
// normalized Z[i], Z[i+NPAIR]; pos[i] = cos/T (fp32).
// ---------------------------------------------------------------------------
__global__ __launch_bounds__(256) void normalize_kernel(
    const float* __restrict__ l1, const float* __restrict__ l2,
    __hip_bfloat16* __restrict__ Z, float* __restrict__ pos) {
  const int i = blockIdx.x;
  const int t = threadIdx.x;           // one float4 per thread
  const float4 a = ((const float4*)(l1 + (size_t)i * DIM))[t];
  const float4 b = ((const float4*)(l2 + (size_t)i * DIM))[t];
  float s1 = a.x*a.x + a.y*a.y + a.z*a.z + a.w*a.w;
  float s2 = b.x*b.x + b.y*b.y + b.z*b.z + b.w*b.w;
  float d  = a.x*b.x + a.y*b.y + a.z*b.z + a.w*b.w;

  #pragma unroll
  for (int off = 32; off; off >>= 1) {
    s1 += __shfl_down(s1, off);
    s2 += __shfl_down(s2, off);
    d  += __shfl_down(d,  off);
  }
  __shared__ float red[3][4];
  __shared__ float fin[3];
  const int wave = t >> 6, lane = t & 63;
  if (lane == 0) { red[0][wave] = s1; red[1][wave] = s2; red[2][wave] = d; }
  __syncthreads();
  if (t == 0) {
    float S1 = red[0][0] + red[0][1] + red[0][2] + red[0][3];
    float S2 = red[1][0] + red[1][1] + red[1][2] + red[1][3];
    float DD = red[2][0] + red[2][1] + red[2][2] + red[2][3];
    float r1 = rsqrtf(S1), r2 = rsqrtf(S2);
    fin[0] = r1; fin[1] = r2;
    pos[i] = DD * r1 * r2 * INV_T;
  }
  __syncthreads();
  const float r1 = fin[0], r2 = fin[1];
  ushort4 za, zb;
  za.x = f2bf(a.x * r1); za.y = f2bf(a.y * r1);
  za.z = f2bf(a.z * r1); za.w = f2bf(a.w * r1);
  zb.x = f2bf(b.x * r2); zb.y = f2bf(b.y * r2);
  zb.z = f2bf(b.z * r2); zb.w = f2bf(b.w * r2);
  ((ushort4*)(Z + (size_t)i * DIM))[t] = za;
  ((ushort4*)(Z + (size_t)(i + NPAIR) * DIM))[t] = zb;
}

// ---------------------------------------------------------------------------
// Kernel B: 256x256 upper-triangular tiles of sim = Z Z^T, 8-phase schedule.
// Epilogue: exp((acc-1)/T) diag-masked; row-sums always, col-sums off-diag.
// ---------------------------------------------------------------------------
__global__ __launch_bounds__(512, 2) void ntxent_gemm_kernel(
    const __hip_bfloat16* __restrict__ Z, float* __restrict__ rowsum) {
  // 8 half-slots of 128x64 bf16 (16 KB): slot = buf*4 + op*2 + half
  // op: 0 = A (rows brow..), 1 = B (rows bcol..). buf = K-tile parity.
  __shared__ __hip_bfloat16 lds[8 * 128 * 64];

  const int t    = threadIdx.x;
  const int wid  = t >> 6;
  const int lane = t & 63;
  const int lrow = lane & 15;
  const int kgrp = lane >> 4;
  const int wm   = wid >> 2;        // 0..1  (M half)
  const int wn   = wid & 3;         // 0..3  (N quarter)
  const int bh   = wn >> 1;         // B half this wave reads
  const int brow0 = (wn & 1) * 64;  // row base within B half

  // T1: bijective XCD-chunk swizzle (528 = 8 * 66), then triangular decode
  const int idx = (blockIdx.x & 7) * 66 + (blockIdx.x >> 3);
  int bj = (int)((sqrtf(8.0f * (float)idx + 1.0f) - 1.0f) * 0.5f);
  while ((bj + 1) * (bj + 2) / 2 <= idx) ++bj;
  while (bj * (bj + 1) / 2 > idx) --bj;
  const int bi = idx - bj * (bj + 1) / 2;
  const int brow = bi * 256, bcol = bj * 256;
  const bool diag = (bi == bj);

#define SLOT(b, o, h) (lds + (((b) << 2 | (o) << 1 | (h)) * 8192))
  const __hip_bfloat16* As0 = SLOT(0, 0, wm);
  const __hip_bfloat16* As1 = SLOT(1, 0, wm);
  const __hip_bfloat16* Bs0 = SLOT(0, 1, bh);
  const __hip_bfloat16* Bs1 = SLOT(1, 1, bh);

  // Stage one 128x64 half-tile: linear LDS dest, inverse-swizzled global src.
  // Chunk c (16B): LDS row c>>3, phys col c&7 holds logical col (c&7)^(row&7).
  auto stage_half = [&](int rowbase, int kt, __hip_bfloat16* slotp) {
    #pragma unroll
    for (int i = 0; i < 2; ++i) {
      const int cb = (wid * 2 + i) * 64;   // wave-uniform chunk base
      const int c  = cb + lane;
      const int r  = c >> 3;
      const int lcol = (c & 7) ^ (r & 7);
      GLOAD_LDS16(Z + (size_t)(rowbase + r) * DIM + kt * 64 + lcol * 8,
                  slotp + cb * 8);
    }
  };
  // Swizzled fragment read: logical (row r, chunk c16) -> phys c16 ^ (r&7).
  auto frag = [&](const __hip_bfloat16* slotp, int r, int c16) -> bf16x8 {
    return *(const bf16x8*)(slotp + r * 64 + (((c16) ^ (r & 7)) * 8));
  };

  bf16x8 af[2][2], bfr[4][2];
  f32x4 acc[8][4];
  #pragma unroll
  for (int i = 0; i < 8; ++i)
    #pragma unroll
    for (int j = 0; j < 4; ++j) acc[i][j] = (f32x4){0.f, 0.f, 0.f, 0.f};

#define DSB(BS)                                                        \
  { _Pragma("unroll") for (int ni = 0; ni < 4; ++ni)                   \
    _Pragma("unroll") for (int kk = 0; kk < 2; ++kk)                   \
      bfr[ni][kk] = frag((BS), brow0 + ni * 16 + lrow, kk * 4 + kgrp); }
#define DSA(Q, AS)                                                     \
  { _Pragma("unroll") for (int e = 0; e < 2; ++e)                      \
    _Pragma("unroll") for (int kk = 0; kk < 2; ++kk)                   \
      af[e][kk] = frag((AS), (2*(Q)+e) * 16 + lrow, kk * 4 + kgrp); }
#define MM(Q)                                                          \
  { __builtin_amdgcn_s_setprio(1);                                     \
    _Pragma("unroll") for (int kk = 0; kk < 2; ++kk)                   \
    _Pragma("unroll") for (int e = 0; e < 2; ++e)                      \
    _Pragma("unroll") for (int ni = 0; ni < 4; ++ni)                   \
      acc[2*(Q)+e][ni] = __builtin_amdgcn_mfma_f32_16x16x32_bf16(      \
          af[e][kk], bfr[ni][kk], acc[2*(Q)+e][ni], 0, 0, 0);          \
    __builtin_amdgcn_s_setprio(0); }

  // Prologue: tile 0 (all 4 halves) + B halves of tile 1, full drain once.
  stage_half(brow,       0, SLOT(0, 0, 0));
  stage_half(brow + 128, 0, SLOT(0, 0, 1));
  stage_half(bcol,       0, SLOT(0, 1, 0));
  stage_half(bcol + 128, 0, SLOT(0, 1, 1));
  stage_half(bcol,       1, SLOT(1, 1, 0));
  stage_half(bcol + 128, 1, SLOT(1, 1, 1));
  asm volatile("s_waitcnt vmcnt(0)" ::: "memory");
  __syncthreads();

  for (int I = 0; I < NITER; ++I) {
    const int t0 = 2 * I, t1 = t0 + 1;
    const bool lastI = (I == NITER - 1);
    // ---- tile t0 (buf0) ----
    // p0: B-frags(t0) + A q0; stage A0(t1)
    DSB(Bs0); DSA(0, As0);
    stage_half(brow,       t1, SLOT(1, 0, 0));
    BAR(); WAITL(); MM(0); BAR();
    // p1: stage A1(t1)
    DSA(1, As0);
    stage_half(brow + 128, t1, SLOT(1, 0, 1));
    BAR(); WAITL(); MM(1); BAR();
    // p2: stage B0(t0+2)  [slot free after p0]
    DSA(2, As0);
    if (!lastI) stage_half(bcol,       t0 + 2, SLOT(0, 1, 0));
    BAR(); WAITL(); MM(2); BAR();
    // p3: stage B1(t0+2); boundary vmcnt drains A(t1) for p4..p7
    DSA(3, As0);
    if (!lastI) stage_half(bcol + 128, t0 + 2, SLOT(0, 1, 1));
    BAR(); WAITL(); MM(3);
    if (lastI) { WAIT_VM(0); } else { WAIT_VM(4); }
    BAR();
    // ---- tile t1 (buf1) ----
    // p4: B-frags(t1) + A q0; stage A0(t0+2)  [slot free after p3]
    DSB(Bs1); DSA(0, As1);
    if (!lastI) stage_half(brow,       t0 + 2, SLOT(0, 0, 0));
    BAR(); WAITL(); MM(0); BAR();
    // p5: stage A1(t0+2)
    DSA(1, As1);
    if (!lastI) stage_half(brow + 128, t0 + 2, SLOT(0, 0, 1));
    BAR(); WAITL(); MM(1); BAR();
    // p6: stage B0(t1+2)  [slot free after p4]
    DSA(2, As1);
    if (!lastI) stage_half(bcol,       t1 + 2, SLOT(1, 1, 0));
    BAR(); WAITL(); MM(2); BAR();
    // p7: stage B1(t1+2); boundary vmcnt drains A(t0+2),B(t0+2) for next iter
    DSA(3, As1);
    if (!lastI) stage_half(bcol + 128, t1 + 2, SLOT(1, 1, 1));
    BAR(); WAITL(); MM(3);
    if (!lastI) { WAIT_VM(4); }
    BAR();
  }

  // Epilogue. C/D layout (m89): col = lane&15, row = (lane>>4)*4 + j.
  // grow = brow + wm*128 + mi*16 + kgrp*4 + j ; gcol = bcol + wn*64 + ni*16 + lrow
  #pragma unroll
  for (int mi = 0; mi < 8; ++mi)
    #pragma unroll
    for (int ni = 0; ni < 4; ++ni) {
      const int gcol = bcol + wn * 64 + ni * 16 + lrow;
      #pragma unroll
      for (int j = 0; j < 4; ++j) {
        const int grow = brow + wm * 128 + mi * 16 + kgrp * 4 + j;
        const float v = acc[mi][ni][j];
        acc[mi][ni][j] = (grow == gcol) ? 0.f : __expf((v - 1.0f) * INV_T);
      }
    }
  // Row sums: reduce ni,j lane-local over ni; shfl over lrow bits.
  #pragma unroll
  for (int mi = 0; mi < 8; ++mi) {
    float rs[4] = {0.f, 0.f, 0.f, 0.f};
    #pragma unroll
    for (int ni = 0; ni < 4; ++ni)
      #pragma unroll
      for (int j = 0; j < 4; ++j) rs[j] += acc[mi][ni][j];
    #pragma unroll
    for (int j = 0; j < 4; ++j) {
      float s = rs[j];
      s += __shfl_xor(s, 1);
      s += __shfl_xor(s, 2);
      s += __shfl_xor(s, 4);
      s += __shfl_xor(s, 8);
      if (lrow == 0)
        atomicAdd(&rowsum[brow + wm * 128 + mi * 16 + kgrp * 4 + j], s);
    }
  }
  // Col sums (off-diag only): reduce mi,j lane-local; shfl over kgrp bits.
  if (!diag) {
    #pragma unroll
    for (int ni = 0; ni < 4; ++ni) {
      float cs = 0.f;
      #pragma unroll
      for (int mi = 0; mi < 8; ++mi)
        cs += acc[mi][ni][0] + acc[mi][ni][1] + acc[mi][ni][2] + acc[mi][ni][3];
      cs += __shfl_xor(cs, 16);
      cs += __shfl_xor(cs, 32);
      if (kgrp == 0)
        atomicAdd(&rowsum[bcol + wn * 64 + ni * 16 + lrow], cs);
    }
  }
}

// ---------------------------------------------------------------------------
// Kernel C: loss = 1/T + mean(log rowsum) - mean(pos)
// ---------------------------------------------------------------------------
__global__ __launch_bounds__(256) void finalize_kernel(
    const float* __restrict__ rowsum, const float* __restrict__ pos,
    float* __restrict__ out) {
  const int t = threadIdx.x;
  float ls = 0.f, ps = 0.f;
  for (int i = t; i < NROWS; i += 256) ls += logf(rowsum[i]);
  for (int i = t; i < NPAIR; i += 256) ps += pos[i];
  #pragma unroll
  for (int off = 32; off; off >>= 1) {
    ls += __shfl_down(ls, off);
    ps += __shfl_down(ps, off);
  }
  __shared__ float sls[4], sps[4];
  const int wave = t >> 6, lane = t & 63;
  if (lane == 0) { sls[wave] = ls; sps[wave] = ps; }
  __syncthreads();
  if (t == 0) {
    const float LS = sls[0] + sls[1] + sls[2] + sls[3];
    const float PS = sps[0] + sps[1] + sps[2] + sps[3];
    out[0] = INV_T + LS / (float)NROWS - PS / (float)NPAIR;
  }
}

extern "C" void kernel_launch(void* const* d_in, const int* in_sizes, int n_in,
                              void* d_out, int out_size, void* d_ws, size_t ws_size,
                              hipStream_t stream) {
  const float* l1 = (const float*)d_in[0];
  const float* l2 = (const float*)d_in[1];
  float* out = (float*)d_out;

  char* ws = (char*)d_ws;
  __hip_bfloat16* Z = (__hip_bfloat16*)ws;                       // 16 MB
  float* rowsum = (float*)(ws + (size_t)NROWS * DIM * 2);        // 32 KB
  float* pos    = rowsum + NROWS;                                // 16 KB

  hipMemsetAsync(rowsum, 0, NROWS * sizeof(float), stream);
  normalize_kernel<<<NPAIR, 256, 0, stream>>>(l1, l2, Z, pos);
  ntxent_gemm_kernel<<<NTRI, 512, 0, stream>>>(Z, rowsum);
  finalize_kernel<<<1, 256, 0, stream>>>(rowsum, pos, out);
}

// Round 4
// 126.009 us; speedup vs baseline: 1.9146x; 1.0486x over previous
//
#include <hip/hip_runtime.h>
#include <hip/hip_bf16.h>

// NT-Xent loss. N=4096 pairs, D=1024, 2N=8192 rows.
// loss = 1/T + mean_i log( sum_{j != i} exp(sim_ij - 1/T) ) - mean_i pos_i
// sim = Z Z^T (cosine); fixed max 1/T (cosine bound) -> no online max.
// R2: triangular tiles (e_ij = e_ji feeds row+col sums).
// R3: 256^2 8-phase -> hit 1-block/CU pigeonhole (528 blocks, 3 rounds).
// R4: 128x256 cells, 8 waves, acc[4][4] (64 regs), BK=32, 3-buffer LDS
//     (72 KB) -> 2 blocks/CU co-residency + fine grid (1056 = 8*132).
//     One barrier per K-tile; counted vmcnt(3); unified gcol>grow rule.

#define NPAIR 4096
#define NROWS 8192
#define DIM   1024
#define NKT   32                    // K-tiles of 32
#define NCELL 1056                  // valid 128x256 cells (bj >= bi>>1)
#define INV_T 14.285714285714286f   // 1/0.07

typedef __attribute__((ext_vector_type(8))) __bf16 bf16x8;
typedef __attribute__((ext_vector_type(4))) float  f32x4;

#define GLOAD_LDS16(g, l)                                              \
  __builtin_amdgcn_global_load_lds(                                    \
      (const __attribute__((address_space(1))) void*)(g),              \
      (__attribute__((address_space(3))) void*)(l), 16, 0, 0)

static __device__ __forceinline__ unsigned short f2bf(float x) {
  unsigned u = __builtin_bit_cast(unsigned, x);
  unsigned r = u + 0x7FFFu + ((u >> 16) & 1u);   // RNE to bf16
  return (unsigned short)(r >> 16);
}

// ---------------------------------------------------------------------------
// Kernel A: per pair-row i: norms + cross dot; write bf16 Z rows; pos[i];
// also zero rowsum (2 entries per block) so no separate memset dispatch.
// ---------------------------------------------------------------------------
__global__ __launch_bounds__(256) void normalize_kernel(
    const float* __restrict__ l1, const float* __restrict__ l2,
    __hip_bfloat16* __restrict__ Z, float* __restrict__ pos,
    float* __restrict__ rowsum) {
  const int i = blockIdx.x;
  const int t = threadIdx.x;           // one float4 per thread
  if (t < 2) rowsum[i * 2 + t] = 0.f;
  const float4 a = ((const float4*)(l1 + (size_t)i * DIM))[t];
  const float4 b = ((const float4*)(l2 + (size_t)i * DIM))[t];
  float s1 = a.x*a.x + a.y*a.y + a.z*a.z + a.w*a.w;
  float s2 = b.x*b.x + b.y*b.y + b.z*b.z + b.w*b.w;
  float d  = a.x*b.x + a.y*b.y + a.z*b.z + a.w*b.w;

  #pragma unroll
  for (int off = 32; off; off >>= 1) {
    s1 += __shfl_down(s1, off);
    s2 += __shfl_down(s2, off);
    d  += __shfl_down(d,  off);
  }
  __shared__ float red[3][4];
  __shared__ float fin[3];
  const int wave = t >> 6, lane = t & 63;
  if (lane == 0) { red[0][wave] = s1; red[1][wave] = s2; red[2][wave] = d; }
  __syncthreads();
  if (t == 0) {
    float S1 = red[0][0] + red[0][1] + red[0][2] + red[0][3];
    float S2 = red[1][0] + red[1][1] + red[1][2] + red[1][3];
    float DD = red[2][0] + red[2][1] + red[2][2] + red[2][3];
    float r1 = rsqrtf(S1), r2 = rsqrtf(S2);
    fin[0] = r1; fin[1] = r2;
    pos[i] = DD * r1 * r2 * INV_T;
  }
  __syncthreads();
  const float r1 = fin[0], r2 = fin[1];
  ushort4 za, zb;
  za.x = f2bf(a.x * r1); za.y = f2bf(a.y * r1);
  za.z = f2bf(a.z * r1); za.w = f2bf(a.w * r1);
  zb.x = f2bf(b.x * r2); zb.y = f2bf(b.y * r2);
  zb.z = f2bf(b.z * r2); zb.w = f2bf(b.w * r2);
  ((ushort4*)(Z + (size_t)i * DIM))[t] = za;
  ((ushort4*)(Z + (size_t)(i + NPAIR) * DIM))[t] = zb;
}

// ---------------------------------------------------------------------------
// Kernel B: 128x256 cells of sim = Z Z^T covering {(i,j): j > i} exactly once.
// Per element: e = (gcol > grow) ? exp((v-1)/T) : 0; emit row-sums AND
// col-sums (each unordered pair feeds both endpoints' rowsum).
// Pipeline: BK=32, 3-buffer LDS, 2-deep prefetch, 1 barrier / K-tile.
// ---------------------------------------------------------------------------
__global__ __launch_bounds__(512, 4) void ntxent_gemm_kernel(
    const __hip_bfloat16* __restrict__ Z, float* __restrict__ rowsum) {
  // buf b at lds + b*12288: A[128][32] (4096 elems) then B[256][32] (8192).
  __shared__ __hip_bfloat16 lds[3 * 12288];   // 72 KB

  const int t    = threadIdx.x;
  const int wid  = t >> 6;
  const int lane = t & 63;
  const int lrow = lane & 15;
  const int kgrp = lane >> 4;
  const int wm   = wid >> 2;        // 0..1: 64-row half of the 128 rows
  const int wn   = wid & 3;         // 0..3: 64-col quarter of the 256 cols

  // T1: bijective XCD swizzle (1056 = 8*132), then cell decode.
  // Cells grouped by m: bi in {2m, 2m+1}, bj in [m, 31]; P(m) = m*(65-m).
  const int c = (blockIdx.x & 7) * 132 + (blockIdx.x >> 3);
  int m = (int)((65.0f - sqrtf(4225.0f - 4.0f * (float)c)) * 0.5f);
  while ((m + 1) * (64 - m) <= c) ++m;
  while (m * (65 - m) > c) --m;
  const int rem = c - m * (65 - m);
  const int n   = 32 - m;
  const int bi  = 2 * m + (rem >= n ? 1 : 0);
  const int bj  = m + rem - (rem >= n ? n : 0);
  const int arow0 = bi * 128;
  const int bcol0 = bj * 256;

  // Stage: linear LDS dest (wave-uniform base + lane*16), chunk-swizzled
  // global source. Row r = 4 chunks of 16B; phys chunk pc holds logical
  // chunk pc ^ ((r>>1)&3)  (2 lanes per 16B bank-slot on read = free).
  auto stageA = [&](int kt, int buf) {
    const int ub = wid * 64;                  // wave-uniform chunk base
    const int cc = ub + lane;
    const int r  = cc >> 2;
    const int sc = (cc & 3) ^ ((r >> 1) & 3);
    GLOAD_LDS16(Z + (size_t)(arow0 + r) * DIM + kt * 32 + sc * 8,
                lds + buf * 12288 + ub * 8);
  };
  auto stageB = [&](int kt, int buf, int half) {
    const int ub = half * 512 + wid * 64;
    const int cc = ub + lane;
    const int r  = cc >> 2;
    const int sc = (cc & 3) ^ ((r >> 1) & 3);
    GLOAD_LDS16(Z + (size_t)(bcol0 + r) * DIM + kt * 32 + sc * 8,
                lds + buf * 12288 + 4096 + ub * 8);
  };
  auto fragA = [&](int buf, int mi) -> bf16x8 {
    const int r  = wm * 64 + mi * 16 + lrow;
    const int ch = kgrp ^ ((r >> 1) & 3);
    return *(const bf16x8*)(lds + buf * 12288 + r * 32 + ch * 8);
  };
  auto fragB = [&](int buf, int ni) -> bf16x8 {
    const int r  = wn * 64 + ni * 16 + lrow;
    const int ch = kgrp ^ ((r >> 1) & 3);
    return *(const bf16x8*)(lds + buf * 12288 + 4096 + r * 32 + ch * 8);
  };

  f32x4 acc[4][4];
  #pragma unroll
  for (int i = 0; i < 4; ++i)
    #pragma unroll
    for (int j = 0; j < 4; ++j) acc[i][j] = (f32x4){0.f, 0.f, 0.f, 0.f};

  // Prologue: stage tiles 0 and 1; drain tile 0 only (vmcnt 3).
  stageA(0, 0); stageB(0, 0, 0); stageB(0, 0, 1);
  stageA(1, 1); stageB(1, 1, 0); stageB(1, 1, 1);
  asm volatile("s_waitcnt vmcnt(3)" ::: "memory");
  __builtin_amdgcn_s_barrier();

  int bcur = 0, bnext = 1, bfree = 2;
  for (int kt = 0; kt < NKT; ++kt) {
    bf16x8 a0 = fragA(bcur, 0), a1 = fragA(bcur, 1);
    bf16x8 a2 = fragA(bcur, 2), a3 = fragA(bcur, 3);
    bf16x8 b0 = fragB(bcur, 0), b1 = fragB(bcur, 1);
    bf16x8 b2 = fragB(bcur, 2), b3 = fragB(bcur, 3);
    if (kt + 2 < NKT) {                      // prefetch 2 ahead into bfree
      stageA(kt + 2, bfree);
      stageB(kt + 2, bfree, 0);
      stageB(kt + 2, bfree, 1);
    }
    asm volatile("s_waitcnt lgkmcnt(0)" ::: "memory");
    __builtin_amdgcn_sched_barrier(0);
    __builtin_amdgcn_s_setprio(1);
    acc[0][0] = __builtin_amdgcn_mfma_f32_16x16x32_bf16(a0, b0, acc[0][0], 0, 0, 0);
    acc[0][1] = __builtin_amdgcn_mfma_f32_16x16x32_bf16(a0, b1, acc[0][1], 0, 0, 0);
    acc[0][2] = __builtin_amdgcn_mfma_f32_16x16x32_bf16(a0, b2, acc[0][2], 0, 0, 0);
    acc[0][3] = __builtin_amdgcn_mfma_f32_16x16x32_bf16(a0, b3, acc[0][3], 0, 0, 0);
    acc[1][0] = __builtin_amdgcn_mfma_f32_16x16x32_bf16(a1, b0, acc[1][0], 0, 0, 0);
    acc[1][1] = __builtin_amdgcn_mfma_f32_16x16x32_bf16(a1, b1, acc[1][1], 0, 0, 0);
    acc[1][2] = __builtin_amdgcn_mfma_f32_16x16x32_bf16(a1, b2, acc[1][2], 0, 0, 0);
    acc[1][3] = __builtin_amdgcn_mfma_f32_16x16x32_bf16(a1, b3, acc[1][3], 0, 0, 0);
    acc[2][0] = __builtin_amdgcn_mfma_f32_16x16x32_bf16(a2, b0, acc[2][0], 0, 0, 0);
    acc[2][1] = __builtin_amdgcn_mfma_f32_16x16x32_bf16(a2, b1, acc[2][1], 0, 0, 0);
    acc[2][2] = __builtin_amdgcn_mfma_f32_16x16x32_bf16(a2, b2, acc[2][2], 0, 0, 0);
    acc[2][3] = __builtin_amdgcn_mfma_f32_16x16x32_bf16(a2, b3, acc[2][3], 0, 0, 0);
    acc[3][0] = __builtin_amdgcn_mfma_f32_16x16x32_bf16(a3, b0, acc[3][0], 0, 0, 0);
    acc[3][1] = __builtin_amdgcn_mfma_f32_16x16x32_bf16(a3, b1, acc[3][1], 0, 0, 0);
    acc[3][2] = __builtin_amdgcn_mfma_f32_16x16x32_bf16(a3, b2, acc[3][2], 0, 0, 0);
    acc[3][3] = __builtin_amdgcn_mfma_f32_16x16x32_bf16(a3, b3, acc[3][3], 0, 0, 0);
    __builtin_amdgcn_s_setprio(0);
    if (kt + 2 < NKT) {
      asm volatile("s_waitcnt vmcnt(3)" ::: "memory");   // drain tile kt+1
    } else if (kt + 1 < NKT) {
      asm volatile("s_waitcnt vmcnt(0)" ::: "memory");   // drain last tile
    }
    __builtin_amdgcn_s_barrier();
    const int tmp = bcur; bcur = bnext; bnext = bfree; bfree = tmp;
  }

  // Epilogue. C/D layout (m89): col = lane&15, row = (lane>>4)*4 + j.
  // Count each unordered pair once: keep only gcol > grow.
  #pragma unroll
  for (int mi = 0; mi < 4; ++mi)
    #pragma unroll
    for (int ni = 0; ni < 4; ++ni) {
      const int gcol = bcol0 + wn * 64 + ni * 16 + lrow;
      #pragma unroll
      for (int j = 0; j < 4; ++j) {
        const int grow = arow0 + wm * 64 + mi * 16 + kgrp * 4 + j;
        const float v = acc[mi][ni][j];
        acc[mi][ni][j] = (gcol > grow) ? __expf((v - 1.0f) * INV_T) : 0.f;
      }
    }
  // Row sums: lane-local over ni, shuffle over lrow bits (1,2,4,8).
  #pragma unroll
  for (int mi = 0; mi < 4; ++mi) {
    float rs[4] = {0.f, 0.f, 0.f, 0.f};
    #pragma unroll
    for (int ni = 0; ni < 4; ++ni)
      #pragma unroll
      for (int j = 0; j < 4; ++j) rs[j] += acc[mi][ni][j];
    #pragma unroll
    for (int j = 0; j < 4; ++j) {
      float s = rs[j];
      s += __shfl_xor(s, 1);
      s += __shfl_xor(s, 2);
      s += __shfl_xor(s, 4);
      s += __shfl_xor(s, 8);
      if (lrow == 0)
        atomicAdd(&rowsum[arow0 + wm * 64 + mi * 16 + kgrp * 4 + j], s);
    }
  }
  // Col sums: lane-local over mi,j, shuffle over kgrp bits (16,32).
  #pragma unroll
  for (int ni = 0; ni < 4; ++ni) {
    float cs = 0.f;
    #pragma unroll
    for (int mi = 0; mi < 4; ++mi)
      cs += acc[mi][ni][0] + acc[mi][ni][1] + acc[mi][ni][2] + acc[mi][ni][3];
    cs += __shfl_xor(cs, 16);
    cs += __shfl_xor(cs, 32);
    if (kgrp == 0)
      atomicAdd(&rowsum[bcol0 + wn * 64 + ni * 16 + lrow], cs);
  }
}

// ---------------------------------------------------------------------------
// Kernel C: loss = 1/T + mean(log rowsum) - mean(pos)   (1024 threads)
// ---------------------------------------------------------------------------
__global__ __launch_bounds__(1024) void finalize_kernel(
    const float* __restrict__ rowsum, const float* __restrict__ pos,
    float* __restrict__ out) {
  const int t = threadIdx.x;
  float ls = 0.f, ps = 0.f;
  for (int i = t; i < NROWS; i += 1024) ls += logf(rowsum[i]);
  for (int i = t; i < NPAIR; i += 1024) ps += pos[i];
  #pragma unroll
  for (int off = 32; off; off >>= 1) {
    ls += __shfl_down(ls, off);
    ps += __shfl_down(ps, off);
  }
  __shared__ float sls[16], sps[16];
  const int wave = t >> 6, lane = t & 63;
  if (lane == 0) { sls[wave] = ls; sps[wave] = ps; }
  __syncthreads();
  if (t == 0) {
    float LS = 0.f, PS = 0.f;
    #pragma unroll
    for (int w = 0; w < 16; ++w) { LS += sls[w]; PS += sps[w]; }
    out[0] = INV_T + LS / (float)NROWS - PS / (float)NPAIR;
  }
}

extern "C" void kernel_launch(void* const* d_in, const int* in_sizes, int n_in,
                              void* d_out, int out_size, void* d_ws, size_t ws_size,
                              hipStream_t stream) {
  const float* l1 = (const float*)d_in[0];
  const float* l2 = (const float*)d_in[1];
  float* out = (float*)d_out;

  char* ws = (char*)d_ws;
  __hip_bfloat16* Z = (__hip_bfloat16*)ws;                       // 16 MB
  float* rowsum = (float*)(ws + (size_t)NROWS * DIM * 2);        // 32 KB
  float* pos    = rowsum + NROWS;                                // 16 KB

  normalize_kernel<<<NPAIR, 256, 0, stream>>>(l1, l2, Z, pos, rowsum);
  ntxent_gemm_kernel<<<NCELL, 512, 0, stream>>>(Z, rowsum);
  finalize_kernel<<<1, 1024, 0, stream>>>(rowsum, pos, out);
}

// Round 5
// 111.355 us; speedup vs baseline: 2.1665x; 1.1316x over previous
//
#include <hip/hip_runtime.h>
#include <hip/hip_bf16.h>

// NT-Xent loss. N=4096 pairs, D=1024, 2N=8192 rows.
// loss = 1/T + mean_i log( sum_{j != i} exp(sim_ij - 1/T) ) - mean_i pos_i
// sim = Z Z^T (cosine); fixed max 1/T (cosine bound) -> no online max.
// R2: triangular tiles (e_ij = e_ji feeds row+col sums).
// R3: 256^2 8-phase pipeline -> best per-round rate (991 TF active) but
//     528 cells / 256 slots = 2.06 -> 3 dispatch rounds -> 69% util.
// R4: 128x256 @ 2 blk/CU -> 1056/512 = 2.06 -> SAME 69% (ratio invariant).
// R5: packing fix. Off-diag = 496 full cells = 2 clean rounds (96.9%);
//     diagonal band peeled into 64 small 128x256 blocks (R4 kernel) ~6us.

#define NPAIR 4096
#define NROWS 8192
#define DIM   1024
#define NOFF  496                   // strict off-diag 256^2 cells (32*31/2)
#define NITER 8                     // 16 K-tiles of 64, 2 per iteration
#define NKT   32                    // K-tiles of 32 (diag kernel)
#define INV_T 14.285714285714286f   // 1/0.07

typedef __attribute__((ext_vector_type(8))) __bf16 bf16x8;
typedef __attribute__((ext_vector_type(4))) float  f32x4;

#define GLOAD_LDS16(g, l)                                              \
  __builtin_amdgcn_global_load_lds(                                    \
      (const __attribute__((address_space(1))) void*)(g),              \
      (__attribute__((address_space(3))) void*)(l), 16, 0, 0)

#define BAR()   __builtin_amdgcn_s_barrier()
#define WAITL() { asm volatile("s_waitcnt lgkmcnt(0)" ::: "memory");   \
                  __builtin_amdgcn_sched_barrier(0); }
#define WAIT_VM(N) asm volatile("s_waitcnt vmcnt(" #N ")" ::: "memory")

static __device__ __forceinline__ unsigned short f2bf(float x) {
  unsigned u = __builtin_bit_cast(unsigned, x);
  unsigned r = u + 0x7FFFu + ((u >> 16) & 1u);   // RNE to bf16
  return (unsigned short)(r >> 16);
}

// ---------------------------------------------------------------------------
// Kernel A: per pair-row i: norms + cross dot; write bf16 Z rows; pos[i];
// zero rowsum (2 entries per block) so no separate memset dispatch.
// ---------------------------------------------------------------------------
__global__ __launch_bounds__(256) void normalize_kernel(
    const float* __restrict__ l1, const float* __restrict__ l2,
    __hip_bfloat16* __restrict__ Z, float* __restrict__ pos,
    float* __restrict__ rowsum) {
  const int i = blockIdx.x;
  const int t = threadIdx.x;           // one float4 per thread
  if (t < 2) rowsum[i * 2 + t] = 0.f;
  const float4 a = ((const float4*)(l1 + (size_t)i * DIM))[t];
  const float4 b = ((const float4*)(l2 + (size_t)i * DIM))[t];
  float s1 = a.x*a.x + a.y*a.y + a.z*a.z + a.w*a.w;
  float s2 = b.x*b.x + b.y*b.y + b.z*b.z + b.w*b.w;
  float d  = a.x*b.x + a.y*b.y + a.z*b.z + a.w*b.w;

  #pragma unroll
  for (int off = 32; off; off >>= 1) {
    s1 += __shfl_down(s1, off);
    s2 += __shfl_down(s2, off);
    d  += __shfl_down(d,  off);
  }
  __shared__ float red[3][4];
  __shared__ float fin[3];
  const int wave = t >> 6, lane = t & 63;
  if (lane == 0) { red[0][wave] = s1; red[1][wave] = s2; red[2][wave] = d; }
  __syncthreads();
  if (t == 0) {
    float S1 = red[0][0] + red[0][1] + red[0][2] + red[0][3];
    float S2 = red[1][0] + red[1][1] + red[1][2] + red[1][3];
    float DD = red[2][0] + red[2][1] + red[2][2] + red[2][3];
    float r1 = rsqrtf(S1), r2 = rsqrtf(S2);
    fin[0] = r1; fin[1] = r2;
    pos[i] = DD * r1 * r2 * INV_T;
  }
  __syncthreads();
  const float r1 = fin[0], r2 = fin[1];
  ushort4 za, zb;
  za.x = f2bf(a.x * r1); za.y = f2bf(a.y * r1);
  za.z = f2bf(a.z * r1); za.w = f2bf(a.w * r1);
  zb.x = f2bf(b.x * r2); zb.y = f2bf(b.y * r2);
  zb.z = f2bf(b.z * r2); zb.w = f2bf(b.w * r2);
  ((ushort4*)(Z + (size_t)i * DIM))[t] = za;
  ((ushort4*)(Z + (size_t)(i + NPAIR) * DIM))[t] = zb;
}

// ---------------------------------------------------------------------------
// Kernel B1: 496 strict off-diagonal 256x256 cells (bi < bj), 8-phase
// pipeline. Every element is a strict pair: e = exp((v-1)/T) unmasked;
// row-sums AND col-sums always.
// ---------------------------------------------------------------------------
__global__ __launch_bounds__(512, 2) void ntxent_gemm_offdiag(
    const __hip_bfloat16* __restrict__ Z, float* __restrict__ rowsum) {
  // 8 half-slots of 128x64 bf16 (16 KB): slot = buf*4 + op*2 + half
  __shared__ __hip_bfloat16 lds[8 * 128 * 64];

  const int t    = threadIdx.x;
  const int wid  = t >> 6;
  const int lane = t & 63;
  const int lrow = lane & 15;
  const int kgrp = lane >> 4;
  const int wm   = wid >> 2;        // 0..1  (M half)
  const int wn   = wid & 3;         // 0..3  (N quarter)
  const int bh   = wn >> 1;         // B half this wave reads
  const int brow0 = (wn & 1) * 64;  // row base within B half

  // T1: bijective XCD-chunk swizzle (496 = 8 * 62), then strict-upper
  // column-major decode: cells (bi,bj), 0 <= bi < bj <= 31.
  const int idx = (blockIdx.x & 7) * 62 + (blockIdx.x >> 3);
  int bj = (int)((1.0f + sqrtf(1.0f + 8.0f * (float)idx)) * 0.5f);
  while (bj * (bj - 1) / 2 > idx) --bj;
  while ((bj + 1) * bj / 2 <= idx) ++bj;
  const int bi = idx - bj * (bj - 1) / 2;
  const int brow = bi * 256, bcol = bj * 256;

#define SLOT(b, o, h) (lds + (((b) << 2 | (o) << 1 | (h)) * 8192))
  const __hip_bfloat16* As0 = SLOT(0, 0, wm);
  const __hip_bfloat16* As1 = SLOT(1, 0, wm);
  const __hip_bfloat16* Bs0 = SLOT(0, 1, bh);
  const __hip_bfloat16* Bs1 = SLOT(1, 1, bh);

  // Stage one 128x64 half-tile: linear LDS dest, inverse-swizzled global src.
  auto stage_half = [&](int rowbase, int kt, __hip_bfloat16* slotp) {
    #pragma unroll
    for (int i = 0; i < 2; ++i) {
      const int cb = (wid * 2 + i) * 64;   // wave-uniform chunk base
      const int c  = cb + lane;
      const int r  = c >> 3;
      const int lcol = (c & 7) ^ (r & 7);
      GLOAD_LDS16(Z + (size_t)(rowbase + r) * DIM + kt * 64 + lcol * 8,
                  slotp + cb * 8);
    }
  };
  auto frag = [&](const __hip_bfloat16* slotp, int r, int c16) -> bf16x8 {
    return *(const bf16x8*)(slotp + r * 64 + (((c16) ^ (r & 7)) * 8));
  };

  bf16x8 af[2][2], bfr[4][2];
  f32x4 acc[8][4];
  #pragma unroll
  for (int i = 0; i < 8; ++i)
    #pragma unroll
    for (int j = 0; j < 4; ++j) acc[i][j] = (f32x4){0.f, 0.f, 0.f, 0.f};

#define DSB(BS)                                                        \
  { _Pragma("unroll") for (int ni = 0; ni < 4; ++ni)                   \
    _Pragma("unroll") for (int kk = 0; kk < 2; ++kk)                   \
      bfr[ni][kk] = frag((BS), brow0 + ni * 16 + lrow, kk * 4 + kgrp); }
#define DSA(Q, AS)                                                     \
  { _Pragma("unroll") for (int e = 0; e < 2; ++e)                      \
    _Pragma("unroll") for (int kk = 0; kk < 2; ++kk)                   \
      af[e][kk] = frag((AS), (2*(Q)+e) * 16 + lrow, kk * 4 + kgrp); }
#define MM(Q)                                                          \
  { __builtin_amdgcn_s_setprio(1);                                     \
    _Pragma("unroll") for (int kk = 0; kk < 2; ++kk)                   \
    _Pragma("unroll") for (int e = 0; e < 2; ++e)                      \
    _Pragma("unroll") for (int ni = 0; ni < 4; ++ni)                   \
      acc[2*(Q)+e][ni] = __builtin_amdgcn_mfma_f32_16x16x32_bf16(      \
          af[e][kk], bfr[ni][kk], acc[2*(Q)+e][ni], 0, 0, 0);          \
    __builtin_amdgcn_s_setprio(0); }

  // Prologue: tile 0 (all 4 halves) + B halves of tile 1, full drain once.
  stage_half(brow,       0, SLOT(0, 0, 0));
  stage_half(brow + 128, 0, SLOT(0, 0, 1));
  stage_half(bcol,       0, SLOT(0, 1, 0));
  stage_half(bcol + 128, 0, SLOT(0, 1, 1));
  stage_half(bcol,       1, SLOT(1, 1, 0));
  stage_half(bcol + 128, 1, SLOT(1, 1, 1));
  asm volatile("s_waitcnt vmcnt(0)" ::: "memory");
  __syncthreads();

  for (int I = 0; I < NITER; ++I) {
    const int t0 = 2 * I, t1 = t0 + 1;
    const bool lastI = (I == NITER - 1);
    // ---- tile t0 (buf0) ----
    DSB(Bs0); DSA(0, As0);
    stage_half(brow,       t1, SLOT(1, 0, 0));
    BAR(); WAITL(); MM(0); BAR();
    DSA(1, As0);
    stage_half(brow + 128, t1, SLOT(1, 0, 1));
    BAR(); WAITL(); MM(1); BAR();
    DSA(2, As0);
    if (!lastI) stage_half(bcol,       t0 + 2, SLOT(0, 1, 0));
    BAR(); WAITL(); MM(2); BAR();
    DSA(3, As0);
    if (!lastI) stage_half(bcol + 128, t0 + 2, SLOT(0, 1, 1));
    BAR(); WAITL(); MM(3);
    if (lastI) { WAIT_VM(0); } else { WAIT_VM(4); }
    BAR();
    // ---- tile t1 (buf1) ----
    DSB(Bs1); DSA(0, As1);
    if (!lastI) stage_half(brow,       t0 + 2, SLOT(0, 0, 0));
    BAR(); WAITL(); MM(0); BAR();
    DSA(1, As1);
    if (!lastI) stage_half(brow + 128, t0 + 2, SLOT(0, 0, 1));
    BAR(); WAITL(); MM(1); BAR();
    DSA(2, As1);
    if (!lastI) stage_half(bcol,       t1 + 2, SLOT(1, 1, 0));
    BAR(); WAITL(); MM(2); BAR();
    DSA(3, As1);
    if (!lastI) stage_half(bcol + 128, t1 + 2, SLOT(1, 1, 1));
    BAR(); WAITL(); MM(3);
    if (!lastI) { WAIT_VM(4); }
    BAR();
  }

  // Epilogue. C/D layout (m89): col = lane&15, row = (lane>>4)*4 + j.
  // Strict off-diag cell: every element is a valid pair, no mask.
  #pragma unroll
  for (int mi = 0; mi < 8; ++mi)
    #pragma unroll
    for (int ni = 0; ni < 4; ++ni)
      #pragma unroll
      for (int j = 0; j < 4; ++j)
        acc[mi][ni][j] = __expf((acc[mi][ni][j] - 1.0f) * INV_T);
  // Row sums.
  #pragma unroll
  for (int mi = 0; mi < 8; ++mi) {
    float rs[4] = {0.f, 0.f, 0.f, 0.f};
    #pragma unroll
    for (int ni = 0; ni < 4; ++ni)
      #pragma unroll
      for (int j = 0; j < 4; ++j) rs[j] += acc[mi][ni][j];
    #pragma unroll
    for (int j = 0; j < 4; ++j) {
      float s = rs[j];
      s += __shfl_xor(s, 1);
      s += __shfl_xor(s, 2);
      s += __shfl_xor(s, 4);
      s += __shfl_xor(s, 8);
      if (lrow == 0)
        atomicAdd(&rowsum[brow + wm * 128 + mi * 16 + kgrp * 4 + j], s);
    }
  }
  // Col sums.
  #pragma unroll
  for (int ni = 0; ni < 4; ++ni) {
    float cs = 0.f;
    #pragma unroll
    for (int mi = 0; mi < 8; ++mi)
      cs += acc[mi][ni][0] + acc[mi][ni][1] + acc[mi][ni][2] + acc[mi][ni][3];
    cs += __shfl_xor(cs, 16);
    cs += __shfl_xor(cs, 32);
    if (kgrp == 0)
      atomicAdd(&rowsum[bcol + wn * 64 + ni * 16 + lrow], cs);
  }
}

// ---------------------------------------------------------------------------
// Kernel B2: diagonal band. 64 cells of 128x256: block b covers rows
// [d*256 + (b&1)*128, +128) x cols [d*256, +256), d = b>>1.
// gcol > grow rule keeps each within-cell strict pair exactly once.
// BK=32, 3-buffer LDS, 2-deep prefetch (R4 pipeline, verified).
// ---------------------------------------------------------------------------
__global__ __launch_bounds__(512, 4) void ntxent_gemm_diag(
    const __hip_bfloat16* __restrict__ Z, float* __restrict__ rowsum) {
  __shared__ __hip_bfloat16 lds[3 * 12288];   // 72 KB

  const int t    = threadIdx.x;
  const int wid  = t >> 6;
  const int lane = t & 63;
  const int lrow = lane & 15;
  const int kgrp = lane >> 4;
  const int wm   = wid >> 2;
  const int wn   = wid & 3;

  const int d = blockIdx.x >> 1;
  const int arow0 = d * 256 + (blockIdx.x & 1) * 128;
  const int bcol0 = d * 256;

  auto stageA = [&](int kt, int buf) {
    const int ub = wid * 64;
    const int cc = ub + lane;
    const int r  = cc >> 2;
    const int sc = (cc & 3) ^ ((r >> 1) & 3);
    GLOAD_LDS16(Z + (size_t)(arow0 + r) * DIM + kt * 32 + sc * 8,
                lds + buf * 12288 + ub * 8);
  };
  auto stageB = [&](int kt, int buf, int half) {
    const int ub = half * 512 + wid * 64;
    const int cc = ub + lane;
    const int r  = cc >> 2;
    const int sc = (cc & 3) ^ ((r >> 1) & 3);
    GLOAD_LDS16(Z + (size_t)(bcol0 + r) * DIM + kt * 32 + sc * 8,
                lds + buf * 12288 + 4096 + ub * 8);
  };
  auto fragA = [&](int buf, int mi) -> bf16x8 {
    const int r  = wm * 64 + mi * 16 + lrow;
    const int ch = kgrp ^ ((r >> 1) & 3);
    return *(const bf16x8*)(lds + buf * 12288 + r * 32 + ch * 8);
  };
  auto fragB = [&](int buf, int ni) -> bf16x8 {
    const int r  = wn * 64 + ni * 16 + lrow;
    const int ch = kgrp ^ ((r >> 1) & 3);
    return *(const bf16x8*)(lds + buf * 12288 + 4096 + r * 32 + ch * 8);
  };

  f32x4 acc[4][4];
  #pragma unroll
  for (int i = 0; i < 4; ++i)
    #pragma unroll
    for (int j = 0; j < 4; ++j) acc[i][j] = (f32x4){0.f, 0.f, 0.f, 0.f};

  stageA(0, 0); stageB(0, 0, 0); stageB(0, 0, 1);
  stageA(1, 1); stageB(1, 1, 0); stageB(1, 1, 1);
  asm volatile("s_waitcnt vmcnt(3)" ::: "memory");
  __builtin_amdgcn_s_barrier();

  int bcur = 0, bnext = 1, bfree = 2;
  for (int kt = 0; kt < NKT; ++kt) {
    bf16x8 a0 = fragA(bcur, 0), a1 = fragA(bcur, 1);
    bf16x8 a2 = fragA(bcur, 2), a3 = fragA(bcur, 3);
    bf16x8 b0 = fragB(bcur, 0), b1 = fragB(bcur, 1);
    bf16x8 b2 = fragB(bcur, 2), b3 = fragB(bcur, 3);
    if (kt + 2 < NKT) {
      stageA(kt + 2, bfree);
      stageB(kt + 2, bfree, 0);
      stageB(kt + 2, bfree, 1);
    }
    asm volatile("s_waitcnt lgkmcnt(0)" ::: "memory");
    __builtin_amdgcn_sched_barrier(0);
    __builtin_amdgcn_s_setprio(1);
    acc[0][0] = __builtin_amdgcn_mfma_f32_16x16x32_bf16(a0, b0, acc[0][0], 0, 0, 0);
    acc[0][1] = __builtin_amdgcn_mfma_f32_16x16x32_bf16(a0, b1, acc[0][1], 0, 0, 0);
    acc[0][2] = __builtin_amdgcn_mfma_f32_16x16x32_bf16(a0, b2, acc[0][2], 0, 0, 0);
    acc[0][3] = __builtin_amdgcn_mfma_f32_16x16x32_bf16(a0, b3, acc[0][3], 0, 0, 0);
    acc[1][0] = __builtin_amdgcn_mfma_f32_16x16x32_bf16(a1, b0, acc[1][0], 0, 0, 0);
    acc[1][1] = __builtin_amdgcn_mfma_f32_16x16x32_bf16(a1, b1, acc[1][1], 0, 0, 0);
    acc[1][2] = __builtin_amdgcn_mfma_f32_16x16x32_bf16(a1, b2, acc[1][2], 0, 0, 0);
    acc[1][3] = __builtin_amdgcn_mfma_f32_16x16x32_bf16(a1, b3, acc[1][3], 0, 0, 0);
    acc[2][0] = __builtin_amdgcn_mfma_f32_16x16x32_bf16(a2, b0, acc[2][0], 0, 0, 0);
    acc[2][1] = __builtin_amdgcn_mfma_f32_16x16x32_bf16(a2, b1, acc[2][1], 0, 0, 0);
    acc[2][2] = __builtin_amdgcn_mfma_f32_16x16x32_bf16(a2, b2, acc[2][2], 0, 0, 0);
    acc[2][3] = __builtin_amdgcn_mfma_f32_16x16x32_bf16(a2, b3, acc[2][3], 0, 0, 0);
    acc[3][0] = __builtin_amdgcn_mfma_f32_16x16x32_bf16(a3, b0, acc[3][0], 0, 0, 0);
    acc[3][1] = __builtin_amdgcn_mfma_f32_16x16x32_bf16(a3, b1, acc[3][1], 0, 0, 0);
    acc[3][2] = __builtin_amdgcn_mfma_f32_16x16x32_bf16(a3, b2, acc[3][2], 0, 0, 0);
    acc[3][3] = __builtin_amdgcn_mfma_f32_16x16x32_bf16(a3, b3, acc[3][3], 0, 0, 0);
    __builtin_amdgcn_s_setprio(0);
    if (kt + 2 < NKT) {
      asm volatile("s_waitcnt vmcnt(3)" ::: "memory");
    } else if (kt + 1 < NKT) {
      asm volatile("s_waitcnt vmcnt(0)" ::: "memory");
    }
    __builtin_amdgcn_s_barrier();
    const int tmp = bcur; bcur = bnext; bnext = bfree; bfree = tmp;
  }

  // Keep only gcol > grow (each within-cell pair once; diagonal excluded).
  #pragma unroll
  for (int mi = 0; mi < 4; ++mi)
    #pragma unroll
    for (int ni = 0; ni < 4; ++ni) {
      const int gcol = bcol0 + wn * 64 + ni * 16 + lrow;
      #pragma unroll
      for (int j = 0; j < 4; ++j) {
        const int grow = arow0 + wm * 64 + mi * 16 + kgrp * 4 + j;
        const float v = acc[mi][ni][j];
        acc[mi][ni][j] = (gcol > grow) ? __expf((v - 1.0f) * INV_T) : 0.f;
      }
    }
  #pragma unroll
  for (int mi = 0; mi < 4; ++mi) {
    float rs[4] = {0.f, 0.f, 0.f, 0.f};
    #pragma unroll
    for (int ni = 0; ni < 4; ++ni)
      #pragma unroll
      for (int j = 0; j < 4; ++j) rs[j] += acc[mi][ni][j];
    #pragma unroll
    for (int j = 0; j < 4; ++j) {
      float s = rs[j];
      s += __shfl_xor(s, 1);
      s += __shfl_xor(s, 2);
      s += __shfl_xor(s, 4);
      s += __shfl_xor(s, 8);
      if (lrow == 0)
        atomicAdd(&rowsum[arow0 + wm * 64 + mi * 16 + kgrp * 4 + j], s);
    }
  }
  #pragma unroll
  for (int ni = 0; ni < 4; ++ni) {
    float cs = 0.f;
    #pragma unroll
    for (int mi = 0; mi < 4; ++mi)
      cs += acc[mi][ni][0] + acc[mi][ni][1] + acc[mi][ni][2] + acc[mi][ni][3];
    cs += __shfl_xor(cs, 16);
    cs += __shfl_xor(cs, 32);
    if (kgrp == 0)
      atomicAdd(&rowsum[bcol0 + wn * 64 + ni * 16 + lrow], cs);
  }
}

// ---------------------------------------------------------------------------
// Kernel C: loss = 1/T + mean(log rowsum) - mean(pos)
// ---------------------------------------------------------------------------
__global__ __launch_bounds__(1024) void finalize_kernel(
    const float* __restrict__ rowsum, const float* __restrict__ pos,
    float* __restrict__ out) {
  const int t = threadIdx.x;
  float ls = 0.f, ps = 0.f;
  for (int i = t; i < NROWS; i += 1024) ls += logf(rowsum[i]);
  for (int i = t; i < NPAIR; i += 1024) ps += pos[i];
  #pragma unroll
  for (int off = 32; off; off >>= 1) {
    ls += __shfl_down(ls, off);
    ps += __shfl_down(ps, off);
  }
  __shared__ float sls[16], sps[16];
  const int wave = t >> 6, lane = t & 63;
  if (lane == 0) { sls[wave] = ls; sps[wave] = ps; }
  __syncthreads();
  if (t == 0) {
    float LS = 0.f, PS = 0.f;
    #pragma unroll
    for (int w = 0; w < 16; ++w) { LS += sls[w]; PS += sps[w]; }
    out[0] = INV_T + LS / (float)NROWS - PS / (float)NPAIR;
  }
}

extern "C" void kernel_launch(void* const* d_in, const int* in_sizes, int n_in,
                              void* d_out, int out_size, void* d_ws, size_t ws_size,
                              hipStream_t stream) {
  const float* l1 = (const float*)d_in[0];
  const float* l2 = (const float*)d_in[1];
  float* out = (float*)d_out;

  char* ws = (char*)d_ws;
  __hip_bfloat16* Z = (__hip_bfloat16*)ws;                       // 16 MB
  float* rowsum = (float*)(ws + (size_t)NROWS * DIM * 2);        // 32 KB
  float* pos    = rowsum + NROWS;                                // 16 KB

  normalize_kernel<<<NPAIR, 256, 0, stream>>>(l1, l2, Z, pos, rowsum);
  ntxent_gemm_offdiag<<<NOFF, 512, 0, stream>>>(Z, rowsum);
  ntxent_gemm_diag<<<64, 512, 0, stream>>>(Z, rowsum);
  finalize_kernel<<<1, 1024, 0, stream>>>(rowsum, pos, out);
}